// Round 4
// baseline (170.965 us; speedup 1.0000x reference)
//
#include <hip/hip_runtime.h>

// SurfNetwork: grid-hash gather + tiny MLP + transmittance cumprod + rgb reduce.
//
// Round-4: saturation test. Each WAVE processes TWO rows back-to-back:
//   issue idxA, idxB, 4 gathers for row0, 4 gathers for row1  (10 loads in
//   flight), compute dW0 for both rows (scalar-path, independent of gathers),
//   then compute row0 (waits only its own 4 gathers; row1's stay in flight),
//   then row1. If duration is unchanged vs R1/R3, the random-gather memory
//   path is saturated at ~3.2 TB/s and we are at the roofline.
//
// Per row: lane t owns samples 2t, 2t+1. Scan wave-local (shfl_up), rgb
// reduce wave-local (shfl_down). No LDS, no barriers.

typedef int   iv4 __attribute__((ext_vector_type(4)));
typedef float fv2 __attribute__((ext_vector_type(2)));

constexpr int WAVES_PER_BLOCK = 4;
constexpr int ROWS_PER_WAVE   = 2;
constexpr int ROWS_PER_BLOCK  = WAVES_PER_BLOCK * ROWS_PER_WAVE;  // 8

__global__ __launch_bounds__(256) void surf_kernel(
    const int*   __restrict__ x,      // [B, 128, 2]
    const float* __restrict__ dvec,   // [B, 16]
    const float* __restrict__ grid,   // [TABLE, 4]
    const float* __restrict__ W0,     // [22, 8] row-major
    const float* __restrict__ W1,     // [8, 3]  row-major
    float*       __restrict__ sigma_out, // [B, 128]
    float*       __restrict__ rgb_out,   // [B, 3]
    int B)
{
    const int lane = threadIdx.x & 63;
    const int wv   = threadIdx.x >> 6;
    const int row0 = __builtin_amdgcn_readfirstlane(
        blockIdx.x * ROWS_PER_BLOCK + wv * ROWS_PER_WAVE);
    if (row0 >= B) return;
    const int row1 = row0 + 1;
    const float4* __restrict__ g4 = (const float4*)grid;

    // ---- issue ALL loads up front (10 VMEM ops in flight) --------------
    const iv4 idxA = __builtin_nontemporal_load((const iv4*)x + (size_t)row0 * 64 + lane);
    const iv4 idxB = __builtin_nontemporal_load((const iv4*)x + (size_t)row1 * 64 + lane);

    float4 fA[4], fB[4];
    fA[0] = g4[idxA.x];  fA[1] = g4[idxA.y];  fA[2] = g4[idxA.z];  fA[3] = g4[idxA.w];
    fB[0] = g4[idxB.x];  fB[1] = g4[idxB.y];  fB[2] = g4[idxB.z];  fB[3] = g4[idxB.w];

    // ---- sample-invariant first-layer partials (independent of gathers) ---
    float dW0A[8], dW0B[8];
    {
        const float* dpA = dvec + (size_t)row0 * 16;
        const float* dpB = dvec + (size_t)row1 * 16;
        #pragma unroll
        for (int j = 0; j < 8; ++j) { dW0A[j] = 0.f; dW0B[j] = 0.f; }
        #pragma unroll
        for (int i = 0; i < 16; ++i) {
            const float w  = W0[i * 8 + 0];  // s_loads; unrolled below
            (void)w;
        }
        #pragma unroll
        for (int i = 0; i < 16; ++i) {
            const float dA = dpA[i];
            const float dB = dpB[i];
            #pragma unroll
            for (int j = 0; j < 8; ++j) {
                const float w = W0[i * 8 + j];
                dW0A[j] = fmaf(dA, w, dW0A[j]);
                dW0B[j] = fmaf(dB, w, dW0B[j]);
            }
        }
    }

    // ---- per-row compute: MLP + scan + outputs --------------------------
    auto process = [&](int row, const float4* f, const float* dW0) {
        float s[2], col[2][3];
        #pragma unroll
        for (int q = 0; q < 2; ++q) {
            const float4 fa = f[2 * q + 0];
            const float4 fb = f[2 * q + 1];
            s[q] = 1.f / (1.f + __expf(-(fa.x * fb.x)));
            const float geo[6] = { fa.y, fa.z, fa.w, fb.y, fb.z, fb.w };
            float h[8];
            #pragma unroll
            for (int j = 0; j < 8; ++j) {
                float acc = dW0[j];
                #pragma unroll
                for (int i = 0; i < 6; ++i)
                    acc = fmaf(geo[i], W0[(16 + i) * 8 + j], acc);
                h[j] = fmaxf(acc, 0.f);
            }
            #pragma unroll
            for (int c = 0; c < 3; ++c) {
                float acc = 0.f;
                #pragma unroll
                for (int k = 0; k < 8; ++k)
                    acc = fmaf(h[k], W1[k * 3 + c], acc);
                col[q][c] = 1.f / (1.f + __expf(-acc));
            }
        }

        // transmittance: inclusive product scan over lanes, shifted.
        const float q0 = 1.f - s[0];
        float p = q0 * (1.f - s[1]);
        #pragma unroll
        for (int off = 1; off < 64; off <<= 1) {
            const float o = __shfl_up(p, off, 64);
            if (lane >= off) p *= o;
        }
        float T0 = __shfl_up(p, 1, 64);
        if (lane == 0) T0 = 1.f;
        const float T1 = T0 * q0;
        const float w0 = T0 * s[0];
        const float w1 = T1 * s[1];

        const fv2 sv = { s[0], s[1] };
        __builtin_nontemporal_store(sv, (fv2*)sigma_out + (size_t)row * 64 + lane);

        float r0 = fmaf(w0, col[0][0], w1 * col[1][0]);
        float r1 = fmaf(w0, col[0][1], w1 * col[1][1]);
        float r2 = fmaf(w0, col[0][2], w1 * col[1][2]);
        #pragma unroll
        for (int off = 32; off > 0; off >>= 1) {
            r0 += __shfl_down(r0, off, 64);
            r1 += __shfl_down(r1, off, 64);
            r2 += __shfl_down(r2, off, 64);
        }
        if (lane == 0) {
            rgb_out[row * 3 + 0] = r0;
            rgb_out[row * 3 + 1] = r1;
            rgb_out[row * 3 + 2] = r2;
        }
    };

    process(row0, fA, dW0A);   // waits fA (vmcnt(4)); fB stays in flight
    process(row1, fB, dW0B);

}

extern "C" void kernel_launch(void* const* d_in, const int* in_sizes, int n_in,
                              void* d_out, int out_size, void* d_ws, size_t ws_size,
                              hipStream_t stream) {
    const int*   x    = (const int*)d_in[0];
    const float* dvec = (const float*)d_in[1];
    const float* grid = (const float*)d_in[2];
    const float* W0   = (const float*)d_in[3];
    const float* W1   = (const float*)d_in[4];

    const int B = in_sizes[1] / 16;          // d is [B, 16]

    float* sigma_out = (float*)d_out;                 // [B, 128]
    float* rgb_out   = sigma_out + (size_t)B * 128;   // [B, 3]

    const int grid_blocks = (B + ROWS_PER_BLOCK - 1) / ROWS_PER_BLOCK;
    surf_kernel<<<grid_blocks, WAVES_PER_BLOCK * 64, 0, stream>>>(
        x, dvec, grid, W0, W1, sigma_out, rgb_out, B);
}